// Round 8
// baseline (308.035 us; speedup 1.0000x reference)
//
#include <hip/hip_runtime.h>

// DFTB Slater-Koster table interpolation.
// Inputs (setup_inputs order):
//   0: rij            [E=2,000,000] float32
//   1: edge_type      [E]           int32
//   2: atom_type      [N=500,000]   int32
//   3: hopping_tables [10,16,512]   float32
//   4: overlap_tables [10,16,512]   float32
//   5: onsiteE        [4,4]         float32
// Outputs (concatenated flat):
//   edge_features [E,16], edge_overlap [E,16], node_features [N,4]
//
// Strategy (evolution R0->R8):
//  * R4: repacked table -> contiguous per-edge reads.  R5: 4 lanes/edge ->
//    4 line-requests/edge, coalesced 1KB NT stores (NT + partial lines
//    amplifies writes - R4 lesson).  R6: 2-edge ILP null (aggregate MLP
//    unchanged).  R7: fp16 null on time -> gather path is TRANSACTION-
//    limited, not byte-limited (~10us per line-request-per-edge; writes
//    floor ~40us).
//  * R8: cut line-requests/edge 4 -> 2 (the minimum: an edge needs 128 B
//    = 2 lines in fp16).  Table repacked PAIR-INTERLEAVED by component:
//    pack2[b][g][m] = (h[g],h[g+1],o[g],o[g+1]) 4 halfs = 8 B, so one
//    128-B row holds all data for an edge.  8 lanes/edge, ONE hx8 16-B
//    load per lane: lanes 0-3 = line 0, lanes 4-7 = line 1 -> 2 coalesced
//    line-requests per edge in a single gather instruction.  Each lane
//    lerps comps 2l,2l+1 of hop and ovl; float2 stores are lane-
//    consecutive -> each store instr = contiguous 512 B of full lines,
//    NT-safe.

#define NGRID 512
#define NUM_INGRLS 16
#define N_BOND_TYPES 10
// pack2: [B][G][M][4] halfs = (h_g, h_g1, o_g, o_g1)
#define PACK2_HALFS (N_BOND_TYPES * NGRID * NUM_INGRLS * 4)   // 327,680 halfs
#define PACK2_BYTES (PACK2_HALFS * 2)                          // 655,360 B

typedef float    fx4 __attribute__((ext_vector_type(4)));
typedef float    fx2 __attribute__((ext_vector_type(2)));
typedef _Float16 hx4 __attribute__((ext_vector_type(4)));
typedef _Float16 hx8 __attribute__((ext_vector_type(8)));

__global__ __launch_bounds__(256) void repack_tables_p2(
    const float* __restrict__ hop,
    const float* __restrict__ ovl,
    _Float16* __restrict__ packed)
{
    int t = blockIdx.x * blockDim.x + threadIdx.x;
    if (t >= N_BOND_TYPES * NGRID * NUM_INGRLS) return;
    int m = t & (NUM_INGRLS - 1);
    int g = (t >> 4) & (NGRID - 1);
    int b = t >> 13;                       // 16*512 = 8192 = 2^13
    int g1 = min(g + 1, NGRID - 1);        // g=511 row is never read (i0<=510)
    const float* hb = hop + ((size_t)b * NUM_INGRLS + m) * NGRID;
    const float* ob = ovl + ((size_t)b * NUM_INGRLS + m) * NGRID;
    hx4 v;
    v[0] = (_Float16)hb[g];
    v[1] = (_Float16)hb[g1];
    v[2] = (_Float16)ob[g];
    v[3] = (_Float16)ob[g1];
    size_t idx = (((size_t)b * NGRID + g) * NUM_INGRLS + m) * 4;
    *(hx4*)(packed + idx) = v;
}

// 8 lanes per edge: lane l loads 16 B (comps 2l, 2l+1: h_g,h_g1,o_g,o_g1
// pairs), lerps, stores float2 into hop and ovl outputs.
__global__ __launch_bounds__(256) void dftb_edge_p2(
    const float* __restrict__ rij,
    const int*   __restrict__ etype,
    const _Float16* __restrict__ packed,   // [10][512][16][4] halfs
    float* __restrict__ out_hop,
    float* __restrict__ out_ovl,
    int E)
{
    const float X0f = 1.0f;
    const float DXf = (float)((10.0 - 1.0) / (NGRID - 1));

    int tid = blockIdx.x * blockDim.x + threadIdx.x;
    int e = tid >> 3;
    int l = tid & 7;
    if (e >= E) return;

    float r = rij[e];
    int   b = etype[e];

    float t  = (r - X0f) / DXf;
    int   i0 = (int)floorf(t);
    i0 = min(max(i0, 0), NGRID - 2);
    float frac = t - (float)i0;
    float w0   = 1.0f - frac;

    // Row byte offset = ((b*512 + i0) * 128); lane l reads bytes [16l, 16l+16).
    const hx8* src = (const hx8*)(packed + ((size_t)b * NGRID + i0) * (NUM_INGRLS * 4)) + l;
    hx8 v = *src;
    // v = (h_g, h_g1, o_g, o_g1) for comp 2l, then for comp 2l+1.

    fx2 hv, ov;
    hv[0] = (float)v[0] * w0 + (float)v[1] * frac;
    ov[0] = (float)v[2] * w0 + (float)v[3] * frac;
    hv[1] = (float)v[4] * w0 + (float)v[5] * frac;
    ov[1] = (float)v[6] * w0 + (float)v[7] * frac;

    // Slot: edge e, comps [2l, 2l+2) -> fx2 index 8*e + l.  Lanes write
    // consecutive fx2 slots -> each store instr = contiguous 512 B.
    size_t slot = (size_t)e * 8 + l;
    __builtin_nontemporal_store(hv, (fx2*)out_hop + slot);
    __builtin_nontemporal_store(ov, (fx2*)out_ovl + slot);
}

// Fallback (original layout, fp32 exact) if workspace is too small.
__global__ __launch_bounds__(256) void dftb_edge_kernel(
    const float* __restrict__ rij,
    const int*   __restrict__ etype,
    const float* __restrict__ hop,
    const float* __restrict__ ovl,
    float* __restrict__ out_hop,
    float* __restrict__ out_ovl,
    int E)
{
    const float X0f = 1.0f;
    const float DXf = (float)((10.0 - 1.0) / (NGRID - 1));

    int e = blockIdx.x * blockDim.x + threadIdx.x;
    if (e >= E) return;

    float r = rij[e];
    int   b = etype[e];

    float t  = (r - X0f) / DXf;
    int   i0 = (int)floorf(t);
    i0 = min(max(i0, 0), NGRID - 2);
    float frac = t - (float)i0;
    float w0   = 1.0f - frac;

    const float* hbase = hop + (size_t)b * (NUM_INGRLS * NGRID) + i0;
    const float* obase = ovl + (size_t)b * (NUM_INGRLS * NGRID) + i0;

    float oh[NUM_INGRLS];
    float oo[NUM_INGRLS];
#pragma unroll
    for (int m = 0; m < NUM_INGRLS; ++m) {
        float y0 = hbase[m * NGRID];
        float y1 = hbase[m * NGRID + 1];
        oh[m] = y0 * w0 + y1 * frac;
        float z0 = obase[m * NGRID];
        float z1 = obase[m * NGRID + 1];
        oo[m] = z0 * w0 + z1 * frac;
    }

    float4* oh4 = (float4*)(out_hop + (size_t)e * NUM_INGRLS);
    float4* oo4 = (float4*)(out_ovl + (size_t)e * NUM_INGRLS);
#pragma unroll
    for (int qq = 0; qq < 4; ++qq) {
        oh4[qq] = make_float4(oh[4*qq+0], oh[4*qq+1], oh[4*qq+2], oh[4*qq+3]);
        oo4[qq] = make_float4(oo[4*qq+0], oo[4*qq+1], oo[4*qq+2], oo[4*qq+3]);
    }
}

__global__ __launch_bounds__(256) void dftb_node_kernel(
    const int*   __restrict__ atype,
    const float* __restrict__ onsiteE,   // [4,4] -> 4 float4 rows
    float* __restrict__ out,             // [N,4]
    int N)
{
    int n = blockIdx.x * blockDim.x + threadIdx.x;
    if (n >= N) return;
    int a = atype[n];
    const float4* src = (const float4*)onsiteE;
    ((float4*)out)[n] = src[a];
}

extern "C" void kernel_launch(void* const* d_in, const int* in_sizes, int n_in,
                              void* d_out, int out_size, void* d_ws, size_t ws_size,
                              hipStream_t stream) {
    const float* rij       = (const float*)d_in[0];
    const int*   edge_type = (const int*)  d_in[1];
    const int*   atom_type = (const int*)  d_in[2];
    const float* hop_tab   = (const float*)d_in[3];
    const float* ovl_tab   = (const float*)d_in[4];
    const float* onsiteE   = (const float*)d_in[5];

    const int E = in_sizes[0];
    const int N = in_sizes[2];

    float* out_hop  = (float*)d_out;
    float* out_ovl  = out_hop + (size_t)E * NUM_INGRLS;
    float* out_node = out_ovl + (size_t)E * NUM_INGRLS;

    if (d_ws != nullptr && ws_size >= PACK2_BYTES) {
        _Float16* packed = (_Float16*)d_ws;
        {
            int total = N_BOND_TYPES * NGRID * NUM_INGRLS;   // 81,920
            dim3 block(256);
            dim3 grid((total + 255) / 256);
            repack_tables_p2<<<grid, block, 0, stream>>>(hop_tab, ovl_tab, packed);
        }
        {
            long long total = 8LL * E;                       // 16,000,000 threads
            dim3 block(256);
            dim3 grid((unsigned)((total + 255) / 256));
            dftb_edge_p2<<<grid, block, 0, stream>>>(
                rij, edge_type, packed, out_hop, out_ovl, E);
        }
    } else {
        dim3 block(256);
        dim3 grid((E + 255) / 256);
        dftb_edge_kernel<<<grid, block, 0, stream>>>(
            rij, edge_type, hop_tab, ovl_tab, out_hop, out_ovl, E);
    }

    {
        dim3 block(256);
        dim3 grid((N + 255) / 256);
        dftb_node_kernel<<<grid, block, 0, stream>>>(
            atom_type, onsiteE, out_node, N);
    }
}